// Round 1
// baseline (55.012 us; speedup 1.0000x reference)
//
#include <hip/hip_runtime.h>
#include <math.h>

#define H 1024
#define V 50257
#define G 3072          // 3*H
#define NB_LOGITS 3142  // ceil(V / 16)

__device__ __forceinline__ float wave_reduce_sum(float v) {
#pragma unroll
    for (int off = 32; off >= 1; off >>= 1)
        v += __shfl_xor(v, off, 64);
    return v;
}

// online softmax merge: (m,s) <- merge((m,s),(mi,si))
__device__ __forceinline__ void sm_merge(float& m, float& s, float mi, float si) {
    if (mi > m) {
        s = s * expf(m - mi) + si;   // note: if m==-inf, s==0 -> 0*0+si = si
        m = mi;
    } else if (si > 0.f) {
        s += si * expf(mi - m);
    }
}

// K1: gi[row] = dot(W_ih[row], relu(emb[id])) + b_ih[row]
//     gh[row] = dot(W_hh[row], hidden)        + b_hh[row]
// one wave per row; 768 blocks x 256 threads (4 waves) covers 3072 rows
__global__ __launch_bounds__(256) void gates_kernel(
    const int* __restrict__ ids, const float* __restrict__ emb,
    const float* __restrict__ hidden,
    const float* __restrict__ W_ih, const float* __restrict__ W_hh,
    const float* __restrict__ b_ih, const float* __restrict__ b_hh,
    float* __restrict__ gi, float* __restrict__ gh)
{
    const int wave = threadIdx.x >> 6;
    const int lane = threadIdx.x & 63;
    const int row  = blockIdx.x * 4 + wave;
    if (row >= G) return;

    const int id = ids[0];
    const float4* xr = (const float4*)(emb + (size_t)id * H);
    const float4* hr = (const float4*)hidden;
    const float4* wi = (const float4*)(W_ih + (size_t)row * H);
    const float4* wh = (const float4*)(W_hh + (size_t)row * H);

    float ai = 0.f, ah = 0.f;
#pragma unroll
    for (int it = 0; it < 4; ++it) {
        const int k = it * 64 + lane;        // 256 float4 per row
        float4 x4 = xr[k];
        x4.x = fmaxf(x4.x, 0.f); x4.y = fmaxf(x4.y, 0.f);
        x4.z = fmaxf(x4.z, 0.f); x4.w = fmaxf(x4.w, 0.f);
        const float4 h4  = hr[k];
        const float4 wi4 = wi[k];
        const float4 wh4 = wh[k];
        ai += wi4.x * x4.x + wi4.y * x4.y + wi4.z * x4.z + wi4.w * x4.w;
        ah += wh4.x * h4.x + wh4.y * h4.y + wh4.z * h4.z + wh4.w * h4.w;
    }
    ai = wave_reduce_sum(ai);
    ah = wave_reduce_sum(ah);
    if (lane == 0) {
        gi[row] = ai + b_ih[row];
        gh[row] = ah + b_hh[row];
    }
}

// K2: GRU gate math, h_new -> ws and d_out hidden slot
__global__ __launch_bounds__(1024) void gru_combine_kernel(
    const float* __restrict__ gi, const float* __restrict__ gh,
    const float* __restrict__ hidden,
    float* __restrict__ hnew, float* __restrict__ out_hidden)
{
    const int j = threadIdx.x;
    const float ir = gi[j],       hr = gh[j];
    const float iz = gi[H + j],   hz = gh[H + j];
    const float in_ = gi[2*H + j], hn = gh[2*H + j];
    const float r = 1.f / (1.f + expf(-(ir + hr)));
    const float z = 1.f / (1.f + expf(-(iz + hz)));
    const float n = tanhf(in_ + r * hn);
    const float h = hidden[j];
    const float out = (1.f - z) * n + z * h;
    hnew[j] = out;
    out_hidden[j] = out;
}

// K3: logits[row] = dot(h_new, W_out[row]) + b_out[row], written to d_out[0..V)
//     plus per-block online-softmax partials (max, sumexp).
// 256 threads = 4 waves; each wave handles 4 consecutive rows -> 16 rows/block.
__global__ __launch_bounds__(256) void logits_kernel(
    const float* __restrict__ hnew, const float* __restrict__ W_out,
    const float* __restrict__ b_out, float* __restrict__ logits,
    float* __restrict__ pmax, float* __restrict__ psum)
{
    __shared__ float hs[H];
    __shared__ float wm[4], wsv[4];

    for (int i = threadIdx.x; i < H; i += 256) hs[i] = hnew[i];
    __syncthreads();

    const int wave = threadIdx.x >> 6;
    const int lane = threadIdx.x & 63;
    const int base = blockIdx.x * 16 + wave * 4;
    const float4* h4 = (const float4*)hs;

    float m = -INFINITY, s = 0.f;
#pragma unroll
    for (int r = 0; r < 4; ++r) {
        const int row = base + r;
        if (row >= V) break;                  // wave-uniform
        const float4* w = (const float4*)(W_out + (size_t)row * H);
        float acc = 0.f;
#pragma unroll
        for (int it = 0; it < 4; ++it) {
            const int k = it * 64 + lane;
            const float4 w4 = w[k];
            const float4 x4 = h4[k];
            acc += w4.x * x4.x + w4.y * x4.y + w4.z * x4.z + w4.w * x4.w;
        }
        acc = wave_reduce_sum(acc);
        if (lane == 0) {
            const float logit = acc + b_out[row];
            logits[row] = logit;
            sm_merge(m, s, logit, 1.f);
        }
    }
    if (lane == 0) { wm[wave] = m; wsv[wave] = s; }
    __syncthreads();
    if (threadIdx.x == 0) {
        float M = wm[0], S = wsv[0];
#pragma unroll
        for (int w2 = 1; w2 < 4; ++w2) sm_merge(M, S, wm[w2], wsv[w2]);
        pmax[blockIdx.x] = M;
        psum[blockIdx.x] = S;
    }
}

// K4: merge all block partials deterministically -> total = m + log(s)
__global__ __launch_bounds__(256) void reduce_kernel(
    const float* __restrict__ pmax, const float* __restrict__ psum,
    float* __restrict__ total)
{
    __shared__ float wm[4], wsv[4];
    const int tid = threadIdx.x;
    float m = -INFINITY, s = 0.f;
    for (int i = tid; i < NB_LOGITS; i += 256)
        sm_merge(m, s, pmax[i], psum[i]);
#pragma unroll
    for (int off = 32; off >= 1; off >>= 1) {
        const float mo = __shfl_xor(m, off, 64);
        const float so = __shfl_xor(s, off, 64);
        sm_merge(m, s, mo, so);
    }
    if ((tid & 63) == 0) { wm[tid >> 6] = m; wsv[tid >> 6] = s; }
    __syncthreads();
    if (tid == 0) {
        float M = wm[0], S = wsv[0];
#pragma unroll
        for (int w2 = 1; w2 < 4; ++w2) sm_merge(M, S, wm[w2], wsv[w2]);
        *total = M + logf(S);
    }
}

// K5: logp = logit - (m + log s), in place on d_out[0..V)
__global__ __launch_bounds__(256) void logp_kernel(
    float* __restrict__ out, const float* __restrict__ total)
{
    const float t = *total;
    const int v = blockIdx.x * 256 + threadIdx.x;
    if (v < V) out[v] -= t;
}

extern "C" void kernel_launch(void* const* d_in, const int* in_sizes, int n_in,
                              void* d_out, int out_size, void* d_ws, size_t ws_size,
                              hipStream_t stream) {
    const int*   ids    = (const int*)  d_in[0];   // works for i32 and LE-i64 (value < 2^31)
    const float* hidden = (const float*)d_in[1];
    const float* emb    = (const float*)d_in[2];
    const float* W_ih   = (const float*)d_in[3];
    const float* W_hh   = (const float*)d_in[4];
    const float* b_ih   = (const float*)d_in[5];
    const float* b_hh   = (const float*)d_in[6];
    const float* W_out  = (const float*)d_in[7];
    const float* b_out  = (const float*)d_in[8];

    float* out = (float*)d_out;        // [0..V) logp, [V..V+H) hidden_out

    float* ws    = (float*)d_ws;
    float* gi    = ws;                 // 3072
    float* gh    = ws + G;             // 3072
    float* hnew  = ws + 2 * G;         // 1024
    float* pmax  = ws + 2 * G + H;     // NB_LOGITS
    float* psum  = pmax + NB_LOGITS;   // NB_LOGITS
    float* total = psum + NB_LOGITS;   // 1

    gates_kernel<<<G / 4, 256, 0, stream>>>(ids, emb, hidden, W_ih, W_hh,
                                            b_ih, b_hh, gi, gh);
    gru_combine_kernel<<<1, 1024, 0, stream>>>(gi, gh, hidden, hnew, out + V);
    logits_kernel<<<NB_LOGITS, 256, 0, stream>>>(hnew, W_out, b_out, out, pmax, psum);
    reduce_kernel<<<1, 256, 0, stream>>>(pmax, psum, total);
    logp_kernel<<<(V + 255) / 256, 256, 0, stream>>>(out, total);
}

// Round 2
// 52.847 us; speedup vs baseline: 1.0410x; 1.0410x over previous
//
#include <hip/hip_runtime.h>
#include <math.h>

#define H 1024
#define V 50257
#define NB_LOGITS 3142  // ceil(V / 16)
#define NB_FINAL 64

__device__ __forceinline__ float wave_reduce_sum(float v) {
#pragma unroll
    for (int off = 32; off >= 1; off >>= 1)
        v += __shfl_xor(v, off, 64);
    return v;
}

// online softmax merge: (m,s) <- merge((m,s),(mi,si))
__device__ __forceinline__ void sm_merge(float& m, float& s, float mi, float si) {
    if (mi > m) {
        s = s * expf(m - mi) + si;   // m==-inf, s==0 -> si
        m = mi;
    } else if (si > 0.f) {
        s += si * expf(mi - m);
    }
}

// K_a: fused gates + GRU combine. One block per hidden index j (1024 blocks,
// 256 threads). Block j computes the 6 dot products touching output j
// (W_ih/W_hh rows j, H+j, 2H+j), then thread 0 does the gate math and writes
// h_new[j] to ws and to the hidden output slot.
__global__ __launch_bounds__(256) void gru_fused_kernel(
    const int* __restrict__ ids, const float* __restrict__ emb,
    const float* __restrict__ hidden,
    const float* __restrict__ W_ih, const float* __restrict__ W_hh,
    const float* __restrict__ b_ih, const float* __restrict__ b_hh,
    float* __restrict__ hnew, float* __restrict__ out_hidden)
{
    const int j = blockIdx.x;           // 0..H-1
    const int t = threadIdx.x;          // 0..255, one float4 per row
    const int wave = t >> 6;
    const int lane = t & 63;

    const int id = ids[0];
    const float4* xr = (const float4*)(emb + (size_t)id * H);
    const float4* hr = (const float4*)hidden;

    float4 x4 = xr[t];
    x4.x = fmaxf(x4.x, 0.f); x4.y = fmaxf(x4.y, 0.f);
    x4.z = fmaxf(x4.z, 0.f); x4.w = fmaxf(x4.w, 0.f);
    const float4 h4 = hr[t];

    float acc[6];
#pragma unroll
    for (int g = 0; g < 3; ++g) {
        const size_t row = (size_t)g * H + j;
        const float4 wi4 = ((const float4*)(W_ih + row * H))[t];
        const float4 wh4 = ((const float4*)(W_hh + row * H))[t];
        acc[2*g]   = wi4.x * x4.x + wi4.y * x4.y + wi4.z * x4.z + wi4.w * x4.w;
        acc[2*g+1] = wh4.x * h4.x + wh4.y * h4.y + wh4.z * h4.z + wh4.w * h4.w;
    }
#pragma unroll
    for (int g = 0; g < 6; ++g) acc[g] = wave_reduce_sum(acc[g]);

    __shared__ float red[4][6];
    if (lane == 0) {
#pragma unroll
        for (int g = 0; g < 6; ++g) red[wave][g] = acc[g];
    }
    __syncthreads();
    if (t == 0) {
        float tt[6];
#pragma unroll
        for (int g = 0; g < 6; ++g)
            tt[g] = red[0][g] + red[1][g] + red[2][g] + red[3][g];
        const float ir = tt[0] + b_ih[j],       hr_ = tt[1] + b_hh[j];
        const float iz = tt[2] + b_ih[H + j],   hz  = tt[3] + b_hh[H + j];
        const float in_ = tt[4] + b_ih[2*H + j], hn = tt[5] + b_hh[2*H + j];
        const float r = 1.f / (1.f + expf(-(ir + hr_)));
        const float z = 1.f / (1.f + expf(-(iz + hz)));
        const float n = tanhf(in_ + r * hn);
        const float h = hidden[j];
        const float out = (1.f - z) * n + z * h;
        hnew[j] = out;
        out_hidden[j] = out;
    }
}

// K_b: logits[row] = dot(h_new, W_out[row]) + b_out[row] -> d_out[0..V),
// plus per-block online-softmax partials (max, sumexp).
// 256 threads = 4 waves; each wave handles 4 consecutive rows -> 16 rows/block.
__global__ __launch_bounds__(256) void logits_kernel(
    const float* __restrict__ hnew, const float* __restrict__ W_out,
    const float* __restrict__ b_out, float* __restrict__ logits,
    float* __restrict__ pmax, float* __restrict__ psum)
{
    __shared__ float hs[H];
    __shared__ float wm[4], wsv[4];

    for (int i = threadIdx.x; i < H; i += 256) hs[i] = hnew[i];
    __syncthreads();

    const int wave = threadIdx.x >> 6;
    const int lane = threadIdx.x & 63;
    const int base = blockIdx.x * 16 + wave * 4;
    const float4* h4 = (const float4*)hs;

    float m = -INFINITY, s = 0.f;
#pragma unroll
    for (int r = 0; r < 4; ++r) {
        const int row = base + r;
        if (row >= V) break;                  // wave-uniform
        const float4* w = (const float4*)(W_out + (size_t)row * H);
        float acc = 0.f;
#pragma unroll
        for (int it = 0; it < 4; ++it) {
            const int k = it * 64 + lane;
            const float4 w4 = w[k];
            const float4 x4 = h4[k];
            acc += w4.x * x4.x + w4.y * x4.y + w4.z * x4.z + w4.w * x4.w;
        }
        acc = wave_reduce_sum(acc);
        if (lane == 0) {
            const float logit = acc + b_out[row];
            logits[row] = logit;
            sm_merge(m, s, logit, 1.f);
        }
    }
    if (lane == 0) { wm[wave] = m; wsv[wave] = s; }
    __syncthreads();
    if (threadIdx.x == 0) {
        float M = wm[0], S = wsv[0];
#pragma unroll
        for (int w2 = 1; w2 < 4; ++w2) sm_merge(M, S, wm[w2], wsv[w2]);
        pmax[blockIdx.x] = M;
        psum[blockIdx.x] = S;
    }
}

// K_c: fused final reduce + logp. Every block deterministically merges all
// NB_LOGITS partials (identical order -> bit-identical total in every block),
// then grid-strides the in-place subtract over d_out[0..V).
__global__ __launch_bounds__(256) void finalize_kernel(
    const float* __restrict__ pmax, const float* __restrict__ psum,
    float* __restrict__ out)
{
    __shared__ float wm[4], wsv[4];
    __shared__ float total_s;
    const int tid = threadIdx.x;

    float m = -INFINITY, s = 0.f;
    for (int i = tid; i < NB_LOGITS; i += 256)
        sm_merge(m, s, pmax[i], psum[i]);
#pragma unroll
    for (int off = 32; off >= 1; off >>= 1) {
        const float mo = __shfl_xor(m, off, 64);
        const float so = __shfl_xor(s, off, 64);
        sm_merge(m, s, mo, so);
    }
    if ((tid & 63) == 0) { wm[tid >> 6] = m; wsv[tid >> 6] = s; }
    __syncthreads();
    if (tid == 0) {
        float M = wm[0], S = wsv[0];
#pragma unroll
        for (int w2 = 1; w2 < 4; ++w2) sm_merge(M, S, wm[w2], wsv[w2]);
        total_s = M + logf(S);
    }
    __syncthreads();
    const float t = total_s;

    for (int v = blockIdx.x * 256 + tid; v < V; v += NB_FINAL * 256)
        out[v] -= t;
}

extern "C" void kernel_launch(void* const* d_in, const int* in_sizes, int n_in,
                              void* d_out, int out_size, void* d_ws, size_t ws_size,
                              hipStream_t stream) {
    const int*   ids    = (const int*)  d_in[0];
    const float* hidden = (const float*)d_in[1];
    const float* emb    = (const float*)d_in[2];
    const float* W_ih   = (const float*)d_in[3];
    const float* W_hh   = (const float*)d_in[4];
    const float* b_ih   = (const float*)d_in[5];
    const float* b_hh   = (const float*)d_in[6];
    const float* W_out  = (const float*)d_in[7];
    const float* b_out  = (const float*)d_in[8];

    float* out = (float*)d_out;        // [0..V) logp, [V..V+H) hidden_out

    float* ws    = (float*)d_ws;
    float* hnew  = ws;                 // H
    float* pmax  = ws + H;             // NB_LOGITS
    float* psum  = pmax + NB_LOGITS;   // NB_LOGITS

    gru_fused_kernel<<<H, 256, 0, stream>>>(ids, emb, hidden, W_ih, W_hh,
                                            b_ih, b_hh, hnew, out + V);
    logits_kernel<<<NB_LOGITS, 256, 0, stream>>>(hnew, W_out, b_out, out, pmax, psum);
    finalize_kernel<<<NB_FINAL, 256, 0, stream>>>(pmax, psum, out);
}